// Round 1
// baseline (114.086 us; speedup 1.0000x reference)
//
#include <hip/hip_runtime.h>
#include <hip/hip_bf16.h>

#define HID   128
#define PBLK  64
#define NPIX  (256*512)
#define LDW   136   // padded LDS row stride (bf16 elems): 272B -> banks advance by 4/row

typedef __attribute__((ext_vector_type(8))) short bf16x8;
typedef __attribute__((ext_vector_type(4))) float f32x4;

__device__ inline float fast_tanh(float x) {
    // tanh(x) = 1 - 2/(exp(2x)+1); saturates correctly for |x| large
    float e = __expf(2.0f * x);
    float r = __builtin_amdgcn_rcpf(e + 1.0f);
    return 1.0f - 2.0f * r;
}

__device__ inline unsigned short f2bf(float f) {
    union { float f; unsigned int u; } v; v.f = f;
    unsigned int r = (v.u + 0x7fffu + ((v.u >> 16) & 1u)) >> 16;
    return (unsigned short)r;
}
__device__ inline float bf2f(unsigned short b) {
    union { float f; unsigned int u; } v; v.u = ((unsigned int)b) << 16;
    return v.f;
}

__global__ __launch_bounds__(512) void fused_net(
    const float* __restrict__ x_in,     // [3][NPIX]
    const float* __restrict__ W_in,     // [128][3]
    const float* __restrict__ W_h,      // [2][128][128]
    const float* __restrict__ r_rec,    // [3][128]
    const float* __restrict__ resp,     // [3][128]
    const float* __restrict__ bias,     // [3][128]
    const float* __restrict__ W_out,    // [3][128]
    const float* __restrict__ resp_out, // [3]
    const float* __restrict__ b_out,    // [3]
    const int*   __restrict__ n_iters_p,
    float* __restrict__ out)            // [3][NPIX]
{
    __shared__ __align__(16) unsigned short Wh_s[2][HID][LDW];   // 69632 B
    __shared__ __align__(16) unsigned short B_s[3][PBLK][LDW];   // 52224 B
    __shared__ __align__(16) unsigned short Wo_s[16][LDW];       //  4352 B
    __shared__ float Win_s[HID * 3];
    __shared__ float r_s[3][HID];
    __shared__ float resp_s[3][HID];
    __shared__ float bias_s[3][HID];
    __shared__ float xs[3][PBLK];

    const int t = threadIdx.x;
    const int pixbase = (int)blockIdx.x * PBLK;
    const int niters = *n_iters_p;

    // ---- stage weights / params / inputs into LDS ----
    for (int idx = t; idx < 2 * HID * HID; idx += 512) {
        int layer = idx >> 14;
        int rem = idx & 16383;
        Wh_s[layer][rem >> 7][rem & 127] = f2bf(W_h[idx]);
    }
    for (int idx = t; idx < 16 * HID; idx += 512) {
        int row = idx >> 7, col = idx & 127;
        Wo_s[row][col] = (row < 3) ? f2bf(W_out[row * HID + col]) : (unsigned short)0;
    }
    if (t < HID * 3) Win_s[t] = W_in[t];
    if (t < 3 * HID) {
        r_s[t >> 7][t & 127]    = r_rec[t];
        resp_s[t >> 7][t & 127] = resp[t];
        bias_s[t >> 7][t & 127] = bias[t];
    }
    if (t < 3 * PBLK) xs[t >> 6][t & 63] = x_in[(t >> 6) * NPIX + pixbase + (t & 63)];
    __syncthreads();

    const int w  = t >> 6;          // wave id 0..7
    const int l  = t & 63;          // lane
    const int lr = l & 15;          // row/col within 16-tile
    const int lg = l >> 4;          // k-group 0..3
    const int rbase = (w >> 1) * 32;  // wave's output-row base (4 groups)
    const int cbase = (w & 1) * 32;   // wave's pixel base     (2 groups)

    for (int it = 0; it < niters; ++it) {
        // ---- layer 0: leaves (K=3) -> h0, pure VALU, writes B_s[0] in place ----
        {
            int h = t & 127;
            float wi0 = Win_s[h * 3 + 0], wi1 = Win_s[h * 3 + 1], wi2 = Win_s[h * 3 + 2];
            float rr = r_s[0][h], rp = resp_s[0][h], bb = bias_s[0][h];
            #pragma unroll
            for (int i = 0; i < 16; ++i) {
                int p = i * 4 + (t >> 7);
                float pre = wi0 * xs[0][p] + wi1 * xs[1][p] + wi2 * xs[2][p];
                if (it > 0) pre += rr * bf2f(B_s[0][p][h]);   // own element: race-free
                B_s[0][p][h] = f2bf(fast_tanh(rp * pre + bb));
            }
        }
        __syncthreads();

        // ---- layers 1,2: 128x128 GEMM via MFMA; src B_s[lay] -> dst B_s[lay+1] ----
        for (int lay = 0; lay < 2; ++lay) {
            f32x4 acc00 = {0.f, 0.f, 0.f, 0.f};
            f32x4 acc01 = {0.f, 0.f, 0.f, 0.f};
            f32x4 acc10 = {0.f, 0.f, 0.f, 0.f};
            f32x4 acc11 = {0.f, 0.f, 0.f, 0.f};
            #pragma unroll
            for (int kb = 0; kb < 4; ++kb) {
                int kofs = kb * 32 + lg * 8;
                bf16x8 a0 = *(const bf16x8*)&Wh_s[lay][rbase + lr][kofs];
                bf16x8 a1 = *(const bf16x8*)&Wh_s[lay][rbase + 16 + lr][kofs];
                bf16x8 b0 = *(const bf16x8*)&B_s[lay][cbase + lr][kofs];
                bf16x8 b1 = *(const bf16x8*)&B_s[lay][cbase + 16 + lr][kofs];
                acc00 = __builtin_amdgcn_mfma_f32_16x16x32_bf16(a0, b0, acc00, 0, 0, 0);
                acc01 = __builtin_amdgcn_mfma_f32_16x16x32_bf16(a0, b1, acc01, 0, 0, 0);
                acc10 = __builtin_amdgcn_mfma_f32_16x16x32_bf16(a1, b0, acc10, 0, 0, 0);
                acc11 = __builtin_amdgcn_mfma_f32_16x16x32_bf16(a1, b1, acc11, 0, 0, 0);
            }
            const int ln = lay + 1;   // dst plane (holds prev iter's value -> recurrent term)
            #pragma unroll
            for (int mt = 0; mt < 2; ++mt) {
                #pragma unroll
                for (int nt = 0; nt < 2; ++nt) {
                    const f32x4 a = (mt == 0) ? (nt == 0 ? acc00 : acc01)
                                              : (nt == 0 ? acc10 : acc11);
                    int p  = cbase + nt * 16 + lr;
                    int hb = rbase + mt * 16 + lg * 4;
                    unsigned short res[4];
                    #pragma unroll
                    for (int r = 0; r < 4; ++r) {
                        int h = hb + r;
                        float pre = a[r];
                        if (it > 0) pre += r_s[ln][h] * bf2f(B_s[ln][p][h]); // own element
                        res[r] = f2bf(fast_tanh(resp_s[ln][h] * pre + bias_s[ln][h]));
                    }
                    unsigned int lo = (unsigned)res[0] | ((unsigned)res[1] << 16);
                    unsigned int hi = (unsigned)res[2] | ((unsigned)res[3] << 16);
                    uint2 v; v.x = lo; v.y = hi;
                    *(uint2*)&B_s[ln][p][hb] = v;   // 8B aligned: hb % 4 == 0, row stride 272B
                }
            }
            __syncthreads();
        }
    }

    // ---- output layer: [3x128] @ h2, one 16x16 MFMA per 16-pixel tile (waves 0..3) ----
    if (w < 4) {
        f32x4 acc = {0.f, 0.f, 0.f, 0.f};
        #pragma unroll
        for (int kb = 0; kb < 4; ++kb) {
            int kofs = kb * 32 + lg * 8;
            bf16x8 a = *(const bf16x8*)&Wo_s[lr][kofs];
            bf16x8 b = *(const bf16x8*)&B_s[2][w * 16 + lr][kofs];
            acc = __builtin_amdgcn_mfma_f32_16x16x32_bf16(a, b, acc, 0, 0, 0);
        }
        int p = pixbase + w * 16 + lr;
        int rowb = lg * 4;
        #pragma unroll
        for (int r = 0; r < 4; ++r) {
            int o = rowb + r;
            if (o < 3) {
                out[o * NPIX + p] = fast_tanh(resp_out[o] * acc[r] + b_out[o]);
            }
        }
    }
}

extern "C" void kernel_launch(void* const* d_in, const int* in_sizes, int n_in,
                              void* d_out, int out_size, void* d_ws, size_t ws_size,
                              hipStream_t stream) {
    const float* x_in     = (const float*)d_in[0];
    const float* W_in     = (const float*)d_in[1];
    const float* W_h      = (const float*)d_in[2];
    const float* r_rec    = (const float*)d_in[3];
    const float* resp     = (const float*)d_in[4];
    const float* bias     = (const float*)d_in[5];
    const float* W_out    = (const float*)d_in[6];
    const float* resp_out = (const float*)d_in[7];
    const float* b_out    = (const float*)d_in[8];
    const int*   n_iters  = (const int*)d_in[9];
    float* out = (float*)d_out;

    dim3 grid(NPIX / PBLK);   // 2048 blocks
    dim3 block(512);
    fused_net<<<grid, block, 0, stream>>>(x_in, W_in, W_h, r_rec, resp, bias,
                                          W_out, resp_out, b_out, n_iters, out);
}

// Round 2
// 71.508 us; speedup vs baseline: 1.5954x; 1.5954x over previous
//
#include <hip/hip_runtime.h>
#include <hip/hip_bf16.h>

#define HID   128
#define PBLK  128
#define NPIX  (256*512)

typedef __attribute__((ext_vector_type(8))) short bf16x8;
typedef __attribute__((ext_vector_type(4))) float f32x4;

__device__ inline unsigned pack2(float a, float b) {
    __hip_bfloat16 lo = __float2bfloat16(a);
    __hip_bfloat16 hi = __float2bfloat16(b);
    unsigned short ul = *reinterpret_cast<unsigned short*>(&lo);
    unsigned short uh = *reinterpret_cast<unsigned short*>(&hi);
    return (unsigned)ul | ((unsigned)uh << 16);
}
__device__ inline float ulo(unsigned u) { union { unsigned u; float f; } v; v.u = u << 16;        return v.f; }
__device__ inline float uhi(unsigned u) { union { unsigned u; float f; } v; v.u = u & 0xffff0000u; return v.f; }

// act = tanh(z) with u = 2z already applied by caller's folded params
__device__ inline float actf(float u) {
    float e = __expf(u);
    return 1.0f - 2.0f * __builtin_amdgcn_rcpf(e + 1.0f);
}

__global__ __launch_bounds__(1024) void fused_net(
    const float* __restrict__ x_in,     // [3][NPIX]
    const float* __restrict__ W_in,     // [128][3]
    const float* __restrict__ W_h,      // [2][128][128]
    const float* __restrict__ r_rec,    // [3][128]
    const float* __restrict__ resp,     // [3][128]
    const float* __restrict__ bias,     // [3][128]
    const float* __restrict__ W_out,    // [3][128]
    const float* __restrict__ resp_out, // [3]
    const float* __restrict__ b_out,    // [3]
    const int*   __restrict__ n_iters_p,
    float* __restrict__ out)            // [3][NPIX]
{
    // Fragment-ordered LDS: 16B chunk c lives at byte c*16; GEMM lane l reads chunk base+l -> conflict-free.
    __shared__ __align__(16) unsigned short Wh_s[2 * 8 * 4 * 64 * 8];   // 65536 B  [lay][rt][kb][lane][8]
    __shared__ __align__(16) unsigned short Wo_s[4 * 64 * 8];           //  4096 B  [kb][lane][8]
    __shared__ __align__(16) unsigned short P0s[8 * 4 * 64 * 8];        // 32768 B  [g][kb][lane][8]
    __shared__ __align__(16) unsigned short P1s[8 * 4 * 64 * 8];        // 32768 B
    __shared__ float4 sp_s[3 * HID];    // {alpha=2*resp, beta=2*resp*r, gamma=2*bias, -} 6144 B
    __shared__ float  Win_s[HID * 4];   // [h][j] padded             2048 B
    __shared__ float  xs[3 * PBLK];     //                           1536 B
    __shared__ float  spo_s[8];         // {2*resp_out[o], 2*b_out[o]}

    const int t = threadIdx.x;
    const int pixbase = (int)blockIdx.x * PBLK;
    const int niters = *n_iters_p;

    // ---------------- staging (once per block) ----------------
    #pragma unroll
    for (int i = 0; i < 4; ++i) {                       // W_h -> bf16 frag chunks; dest chunk == c
        int c = t + i * 1024;
        int l = c & 63, kb = (c >> 6) & 3, rt = (c >> 8) & 7, lay = (c >> 11) & 1;
        int row = rt * 16 + (l & 15), k = kb * 32 + (l >> 4) * 8;
        const float* src = W_h + ((lay * HID + row) * HID + k);
        float4 f0 = *(const float4*)src;
        float4 f1 = *(const float4*)(src + 4);
        uint4 v;
        v.x = pack2(f0.x, f0.y); v.y = pack2(f0.z, f0.w);
        v.z = pack2(f1.x, f1.y); v.w = pack2(f1.z, f1.w);
        *(uint4*)(Wh_s + c * 8) = v;
    }
    if (t < 256) {                                      // W_out padded to 16 rows
        int c = t;
        int l = c & 63, kb = c >> 6;
        int row = l & 15, k = kb * 32 + (l >> 4) * 8;
        uint4 v = {0u, 0u, 0u, 0u};
        if (row < 3) {
            const float* src = W_out + row * HID + k;
            float4 f0 = *(const float4*)src;
            float4 f1 = *(const float4*)(src + 4);
            v.x = pack2(f0.x, f0.y); v.y = pack2(f0.z, f0.w);
            v.z = pack2(f1.x, f1.y); v.w = pack2(f1.z, f1.w);
        }
        *(uint4*)(Wo_s + c * 8) = v;
    }
    if (t < 3 * HID) {                                  // folded activation params
        float rp = resp[t];
        float4 pv;
        pv.x = 2.0f * rp;
        pv.y = 2.0f * rp * r_rec[t];
        pv.z = 2.0f * bias[t];
        pv.w = 0.0f;
        sp_s[t] = pv;
    }
    if (t < 3 * HID) Win_s[(t / 3) * 4 + (t % 3)] = W_in[t];
    if (t < 3 * PBLK) xs[t] = x_in[(t >> 7) * NPIX + pixbase + (t & 127)];
    if (t < 3) { spo_s[t * 2] = 2.0f * resp_out[t]; spo_s[t * 2 + 1] = 2.0f * b_out[t]; }
    __syncthreads();

    const int w  = t >> 6, l = t & 63;
    const int lr = l & 15, lg = l >> 4;
    const int rt2 = w >> 2;           // row-block 0..3 (32 rows)
    const int ct  = w & 3;            // col-block 0..3 (32 px)

    // L0 mapping: thread owns pixel p0, h-run of 16 at hb2*16
    const int p0  = t & 127;
    const int hb2 = t >> 7;

    // c1[c] = alpha*(W_in x) + gamma  (iteration-invariant)
    float c1[16];
    {
        float x0 = xs[p0], x1 = xs[128 + p0], x2 = xs[256 + p0];
        #pragma unroll
        for (int c = 0; c < 16; ++c) {
            int h = hb2 * 16 + c;
            float base = Win_s[h * 4 + 0] * x0 + Win_s[h * 4 + 1] * x1 + Win_s[h * 4 + 2] * x2;
            float4 pv = sp_s[h];
            c1[c] = pv.x * base + pv.z;
        }
    }

    unsigned rec0[8], rec1[8], rec2[8];
    #pragma unroll
    for (int i = 0; i < 8; ++i) { rec0[i] = 0u; rec1[i] = 0u; rec2[i] = 0u; }

    const bf16x8* WHC = (const bf16x8*)Wh_s;
    const bf16x8* P0c = (const bf16x8*)P0s;
    const bf16x8* P1c = (const bf16x8*)P1s;

    auto do_layer = [&](int lay, const bf16x8* Sc, unsigned short* Dbase,
                        const float4* spL, unsigned* rec, bool dowrite) {
        f32x4 acc00{0,0,0,0}, acc01{0,0,0,0}, acc10{0,0,0,0}, acc11{0,0,0,0};
        const bf16x8* WA = WHC + ((lay * 8 + rt2 * 2) * 4) * 64 + l;
        const bf16x8* SB = Sc + (ct * 2 * 4) * 64 + l;
        #pragma unroll
        for (int kb = 0; kb < 4; ++kb) {
            bf16x8 a0 = WA[kb * 64];
            bf16x8 a1 = WA[(4 + kb) * 64];
            bf16x8 b0 = SB[kb * 64];
            bf16x8 b1 = SB[(4 + kb) * 64];
            acc00 = __builtin_amdgcn_mfma_f32_16x16x32_bf16(a0, b0, acc00, 0, 0, 0);
            acc01 = __builtin_amdgcn_mfma_f32_16x16x32_bf16(a0, b1, acc01, 0, 0, 0);
            acc10 = __builtin_amdgcn_mfma_f32_16x16x32_bf16(a1, b0, acc10, 0, 0, 0);
            acc11 = __builtin_amdgcn_mfma_f32_16x16x32_bf16(a1, b1, acc11, 0, 0, 0);
        }
        #pragma unroll
        for (int mt = 0; mt < 2; ++mt) {
            float4 prm[4];
            #pragma unroll
            for (int r = 0; r < 4; ++r) prm[r] = spL[rt2 * 32 + mt * 16 + lg * 4 + r];
            #pragma unroll
            for (int nt = 0; nt < 2; ++nt) {
                f32x4 a = mt ? (nt ? acc11 : acc10) : (nt ? acc01 : acc00);
                const int di = mt * 4 + nt * 2;
                float r0 = ulo(rec[di]),     r1 = uhi(rec[di]);
                float r2 = ulo(rec[di + 1]), r3 = uhi(rec[di + 1]);
                float v0 = actf(prm[0].x * a[0] + prm[0].y * r0 + prm[0].z);
                float v1 = actf(prm[1].x * a[1] + prm[1].y * r1 + prm[1].z);
                float v2 = actf(prm[2].x * a[2] + prm[2].y * r2 + prm[2].z);
                float v3 = actf(prm[3].x * a[3] + prm[3].y * r3 + prm[3].z);
                unsigned d0 = pack2(v0, v1), d1 = pack2(v2, v3);
                rec[di] = d0; rec[di + 1] = d1;
                if (dowrite) {
                    int chunk = ((ct * 2 + nt) * 4 + rt2) * 64 + (2 * mt + (lg >> 1)) * 16 + lr;
                    uint2 v; v.x = d0; v.y = d1;
                    *(uint2*)(Dbase + chunk * 8 + (lg & 1) * 4) = v;
                }
            }
        }
    };

    for (int it = 0; it < niters; ++it) {
        // ---- L0: leaves -> h0 (VALU), write frag-ordered bf16 into P0 ----
        #pragma unroll
        for (int s = 0; s < 2; ++s) {
            unsigned o0, o1, o2, o3;
            #pragma unroll
            for (int q = 0; q < 4; ++q) {
                int c = s * 8 + q * 2;
                int h = hb2 * 16 + c;
                float b0 = sp_s[h].y, b1 = sp_s[h + 1].y;
                unsigned rp = rec0[s * 4 + q];
                float v0 = actf(c1[c]     + b0 * ulo(rp));
                float v1 = actf(c1[c + 1] + b1 * uhi(rp));
                unsigned pk = pack2(v0, v1);
                rec0[s * 4 + q] = pk;
                if (q == 0) o0 = pk; else if (q == 1) o1 = pk; else if (q == 2) o2 = pk; else o3 = pk;
            }
            int h8 = hb2 * 16 + s * 8;
            int chunk = ((p0 >> 4) * 4 + (h8 >> 5)) * 64 + ((h8 >> 3) & 3) * 16 + (p0 & 15);
            uint4 v; v.x = o0; v.y = o1; v.z = o2; v.w = o3;
            *(uint4*)(P0s + chunk * 8) = v;
        }
        __syncthreads();

        // ---- layer 1: h1 = tanh-affine(W_h[0] @ h0), P0 -> P1 ----
        do_layer(0, P0c, P1s, sp_s + HID, rec1, true);
        __syncthreads();

        // ---- layer 2: h2, P1 -> P0 (plane write only needed on last iter) ----
        do_layer(1, P1c, P0s, sp_s + 2 * HID, rec2, it == niters - 1);
        __syncthreads();
    }

    // ---- output layer: 16(3)-row GEMM over h2 in P0; waves 0..7, one 16-px group each ----
    if (w < 8) {
        f32x4 acc{0, 0, 0, 0};
        const bf16x8* OA = (const bf16x8*)Wo_s + l;
        const bf16x8* OB = P0c + (w * 4) * 64 + l;
        #pragma unroll
        for (int kb = 0; kb < 4; ++kb)
            acc = __builtin_amdgcn_mfma_f32_16x16x32_bf16(OA[kb * 64], OB[kb * 64], acc, 0, 0, 0);
        int p = pixbase + w * 16 + lr;
        #pragma unroll
        for (int r = 0; r < 4; ++r) {
            int o = lg * 4 + r;
            if (o < 3) out[o * NPIX + p] = actf(spo_s[o * 2] * acc[r] + spo_s[o * 2 + 1]);
        }
    }
}

extern "C" void kernel_launch(void* const* d_in, const int* in_sizes, int n_in,
                              void* d_out, int out_size, void* d_ws, size_t ws_size,
                              hipStream_t stream) {
    const float* x_in     = (const float*)d_in[0];
    const float* W_in     = (const float*)d_in[1];
    const float* W_h      = (const float*)d_in[2];
    const float* r_rec    = (const float*)d_in[3];
    const float* resp     = (const float*)d_in[4];
    const float* bias     = (const float*)d_in[5];
    const float* W_out    = (const float*)d_in[6];
    const float* resp_out = (const float*)d_in[7];
    const float* b_out    = (const float*)d_in[8];
    const int*   n_iters  = (const int*)d_in[9];
    float* out = (float*)d_out;

    dim3 grid(NPIX / PBLK);   // 1024 blocks
    dim3 block(1024);
    fused_net<<<grid, block, 0, stream>>>(x_in, W_in, W_h, r_rec, resp, bias,
                                          W_out, resp_out, b_out, n_iters, out);
}